// Round 6
// baseline (535.039 us; speedup 1.0000x reference)
//
#include <hip/hip_runtime.h>
#include <hip/hip_bf16.h>
#include <math.h>

// ChamferLoss: pred [32,4096,3] f32, gt [32,4096,3] f32 -> scalar f32.
//
// d2(q,t) = p2 + (t2 - 2*q.t); min over t needs only (t2 - 2*q.t); p2 and
// sqrt applied once per query. Inner cost: 3 v_fma + 1/2 v_min3 per pair
// = 3.5 lane-ops/pair -> issue floor 47.8 us on 256 CU (fp32 peak 157 TF is
// scalar v_fma at 2cyc; v_pk_fma_f32 is 4cyc -- R4/R5 packing was a no-op).
//
// R5 post-mortem: LDS pipe (ds_read_b128 ~12cyc x 8 waves/CU) co-limited
// with VALU and 2 waves/SIMD pinned -> VALUBusy 67%; plus 54us of
// memset+finish+merge overhead outside the main kernel.
//
// R6: no LDS at all. Prep kernel packs target features (-2x,-2y,-2z,t2)
// as float4 into ws; main kernel reads them with a WAVE-UNIFORM index ->
// scalar/broadcast loads on the SMEM/VMEM pipes, VALU runs free. tsplit=1:
// every thread finishes its query's min locally -> sqrt -> block reduce ->
// one atomicAdd. Two dispatches total; prep zeroes out[0] (stream-ordered
// before main).

#define TPB   256
#define NPTS  4096
#define NB    (32 * NPTS)          // 131072 points per tensor
#define NQTOT (2 * NB)             // 262144 query slots

// ---- prep: pack features for both target sets; also zero the output ----
// feat[0      .. NB-1 ] = gt   (targets for dir 0: queries = pred)
// feat[NB .. 2*NB - 1 ] = pred (targets for dir 1: queries = gt)
__global__ __launch_bounds__(TPB) void chamfer_prep(
    const float* __restrict__ pred,
    const float* __restrict__ gt,
    float4* __restrict__ feat,
    float* __restrict__ out)
{
    const int tid = threadIdx.x;
    if (blockIdx.x == 0 && tid == 0) out[0] = 0.0f;

    // 64 blocks x 256 threads x 16 points = 262144
    const int base = blockIdx.x * (TPB * 16);
#pragma unroll
    for (int k = 0; k < 16; ++k) {
        const int P = base + k * TPB + tid;
        const float* src = (P < NB) ? (gt + (size_t)P * 3)
                                    : (pred + (size_t)(P - NB) * 3);
        float x = src[0], y = src[1], z = src[2];
        feat[P] = make_float4(-2.0f * x, -2.0f * y, -2.0f * z,
                              fmaf(x, x, fmaf(y, y, z * z)));
    }
}

// ---- main: 1 query per thread, all 4096 targets, uniform feature loads ----
__global__ __launch_bounds__(TPB) void chamfer_main(
    const float* __restrict__ pred,
    const float* __restrict__ gt,
    const float4* __restrict__ feat,
    float* __restrict__ out)
{
    // grid.x = 1024: qsplit (16, fast) x batch (32) x dir (2, slow)
    const int bx  = blockIdx.x;
    const int qs  = bx & 15;
    const int rem = bx >> 4;
    const int b   = rem & 31;
    const int dir = rem >> 5;

    const int tid = threadIdx.x;

    // queries: dir0 = pred[b], dir1 = gt[b]; coalesced (stride-3 floats)
    const float* __restrict__ q =
        (dir ? gt : pred) + (size_t)(b * NPTS + qs * TPB + tid) * 3;
    const float qx = q[0], qy = q[1], qz = q[2];

    // targets: feature slab for this (dir, b) — wave-uniform address stream
    const float4* __restrict__ tf = feat + (size_t)dir * NB + (size_t)b * NPTS;

    float mn = 1e30f;
#pragma unroll 8
    for (int j = 0; j < NPTS; j += 2) {
        const float4 g0 = tf[j];
        const float4 g1 = tf[j + 1];
        float d0 = fmaf(qx, g0.x, fmaf(qy, g0.y, fmaf(qz, g0.z, g0.w)));
        float d1 = fmaf(qx, g1.x, fmaf(qy, g1.y, fmaf(qz, g1.z, g1.w)));
        mn = fminf(fminf(d0, d1), mn);   // v_min3_f32
    }

    const float p2 = fmaf(qx, qx, fmaf(qy, qy, qz * qz));
    float s = sqrtf(fmaxf(mn + p2, 1e-12f));

    // 64-lane shuffle reduce, then cross-wave via LDS, one atomicAdd/block
    __shared__ float swave[TPB / 64];
#pragma unroll
    for (int off = 32; off > 0; off >>= 1)
        s += __shfl_down(s, off, 64);
    const int wid = tid >> 6, lane = tid & 63;
    if (lane == 0) swave[wid] = s;
    __syncthreads();
    if (tid == 0) {
        float tot = swave[0] + swave[1] + swave[2] + swave[3];
        atomicAdd(out, tot * (1.0f / 131072.0f));
    }
}

extern "C" void kernel_launch(void* const* d_in, const int* in_sizes, int n_in,
                              void* d_out, int out_size, void* d_ws, size_t ws_size,
                              hipStream_t stream)
{
    const float* pred = (const float*)d_in[0];
    const float* gt   = (const float*)d_in[1];
    float* out        = (float*)d_out;
    float4* feat      = (float4*)d_ws;   // 4 MB

    chamfer_prep<<<dim3(NQTOT / (TPB * 16)), dim3(TPB), 0, stream>>>(
        pred, gt, feat, out);
    chamfer_main<<<dim3(NQTOT / TPB), dim3(TPB), 0, stream>>>(
        pred, gt, feat, out);
}

// Round 7
// 148.576 us; speedup vs baseline: 3.6011x; 3.6011x over previous
//
#include <hip/hip_runtime.h>
#include <hip/hip_bf16.h>
#include <math.h>

// ChamferLoss: pred [32,4096,3] f32, gt [32,4096,3] f32 -> scalar f32.
//
// d2(q,t) = p2 + (t2 - 2 q.t); min over t folds only (t2 - 2 q.t); p2 and
// sqrt once per query (sqrt monotone). Inner: 3 v_fma + 1/2 v_min3 per pair
// = 3.5 insts x 2cyc -> issue floor 47.8 us on 1024 SIMDs.
//
// R4/R5 post-mortem: v_pk_fma_f32 issues at 8 cyc (half the scalar fp32
// FLOP rate): predicted 88.7 us == measured 88.5. Scalar v_fma (2cyc) is
// the 157TF path. R6 post-mortem: "uniform" VMEM loads are per-lane loads;
// QPT=1 serialized on VMEM latency -> 488 us. LDS broadcast is right.
//
// R7: scalar fma+min3, QPT=16 (LDS pipe 43% of VALU), grid 1024 =
// dir(2) x batch(32) x tsplit(16), TCH=256 (4KB LDS), waves_per_eu(4,4)
// -> 4 blocks/CU, VGPR cap 128 (need ~100, no AGPR shuffle).
// Single compute dispatch: tsplit merge via device atomicMin (uint order ==
// float order for d2>0); per-(dir,b) completion counter elects a finisher
// block that does sqrt+sum for its 4096 queries; global counter elects the
// last finisher to sum 64 partials and store out[0]. Counters/mins all init
// 0xFF by ONE memset (counter wrap math handles 0xFFFFFFFF start).

#define TPB   256
#define QPT   16            // all 4096 queries of (dir,b) per block
#define NPTS  4096
#define TSPL  16
#define TCH   (NPTS / TSPL) // 256 targets per block
#define NGRP  64            // (dir,b) groups
#define NQTOT (2 * 32 * NPTS)

// ws layout (bytes):
//   [0, 1MB)            : uint mins[262144]            (init 0xFF)
//   [1MB, +256)         : uint cnt[64]                 (init 0xFF)
//   [1MB+256, +256)     : float partial[64]            (overwritten)
//   [1MB+512, +4)       : uint gcount                  (init 0xFF)
#define WS_CTRL (NQTOT * 4)
#define WS_INIT (WS_CTRL + 512 + 4)

__global__ __attribute__((amdgpu_flat_work_group_size(TPB, TPB)))
__attribute__((amdgpu_waves_per_eu(4, 4)))
void chamfer_fused(const float* __restrict__ pred,
                   const float* __restrict__ gt,
                   unsigned int* __restrict__ ws,
                   float* __restrict__ out)
{
    // grid.x = 1024: dir (2) x batch (32) x tsplit (16)
    const int bx  = blockIdx.x;
    const int dir = bx >> 9;
    const int rem = bx & 511;
    const int b   = rem >> 4;
    const int kt  = rem & 15;
    const int g   = dir * 32 + b;

    unsigned int* mins    = ws;
    unsigned int* cnt     = ws + NQTOT;
    float*        partial = (float*)(ws + NQTOT + 64);
    unsigned int* gcount  = ws + NQTOT + 128;

    const float* __restrict__ qbase = (dir ? gt : pred) + (size_t)b * NPTS * 3;
    const float* __restrict__ tbase = (dir ? pred : gt) + (size_t)b * NPTS * 3;

    __shared__ float4 sT[TCH];          // (-2x,-2y,-2z, t2)  4 KB
    __shared__ float swave[TPB / 64];
    __shared__ unsigned int sflag1, sflag2;

    const int tid = threadIdx.x;
    if (tid == 0) { sflag1 = 0u; sflag2 = 0u; }

    // Stage this block's 256-target slice: 1 point per thread
    {
        const float* tp = tbase + (size_t)(kt * TCH + tid) * 3;
        float x = tp[0], y = tp[1], z = tp[2];
        sT[tid] = make_float4(-2.0f * x, -2.0f * y, -2.0f * z,
                              fmaf(x, x, fmaf(y, y, z * z)));
    }

    // 16 queries per thread
    float qx[QPT], qy[QPT], qz[QPT], mn[QPT];
#pragma unroll
    for (int i = 0; i < QPT; ++i) {
        const float* q = qbase + (size_t)(i * TPB + tid) * 3;
        qx[i] = q[0]; qy[i] = q[1]; qz[i] = q[2];
        mn[i] = 1e30f;
    }

    __syncthreads();

    // 2 targets/iter: per query 6 v_fma + 1 v_min3 -> 112 VALU insts per
    // 2 ds_read_b128 (LDS pipe at 43% of VALU issue).
#pragma unroll 2
    for (int j = 0; j < TCH; j += 2) {
        const float4 g0 = sT[j];
        const float4 g1 = sT[j + 1];
#pragma unroll
        for (int i = 0; i < QPT; ++i) {
            float d0 = fmaf(qx[i], g0.x, fmaf(qy[i], g0.y,
                       fmaf(qz[i], g0.z, g0.w)));
            float d1 = fmaf(qx[i], g1.x, fmaf(qy[i], g1.y,
                       fmaf(qz[i], g1.z, g1.w)));
            mn[i] = fminf(fminf(d0, d1), mn[i]);   // v_min3_f32
        }
    }

    // Merge partial mins across the 16 tsplit siblings (d2 > 0 -> uint
    // bit-pattern order == float order; slots init 0xFFFFFFFF = uint max).
    unsigned int* wq = mins + (size_t)g * NPTS;
#pragma unroll
    for (int i = 0; i < QPT; ++i) {
        float p2 = fmaf(qx[i], qx[i], fmaf(qy[i], qy[i], qz[i] * qz[i]));
        float d2 = fmaxf(mn[i] + p2, 1e-12f);
        atomicMin(&wq[i * TPB + tid], __float_as_uint(d2));
    }

    // Group completion: 16th arriver (old == 0xFFFFFFFF + 15 = 14) finishes.
    __syncthreads();          // drains this block's atomics (vmcnt at barrier)
    if (tid == 0) {
        __threadfence();
        unsigned int old = atomicAdd(&cnt[g], 1u);
        if (old == 14u) sflag1 = 1u;
    }
    __syncthreads();

    float s = 0.0f;
    if (sflag1) {
        // This block finishes (dir,b): sqrt + sum its 4096 merged mins.
        // atomic RMW reads go to the device coherence point (no stale L2).
#pragma unroll
        for (int r = 0; r < QPT; ++r) {
            unsigned int u = atomicAdd(&wq[r * TPB + tid], 0u);
            s += sqrtf(__uint_as_float(u));
        }
    }
    // Block reduce (all blocks participate; non-finishers reduce zeros)
#pragma unroll
    for (int off = 32; off > 0; off >>= 1)
        s += __shfl_down(s, off, 64);
    const int wid = tid >> 6, lane = tid & 63;
    if (lane == 0) swave[wid] = s;
    __syncthreads();
    if (tid == 0 && sflag1) {
        float tot = swave[0] + swave[1] + swave[2] + swave[3];
        atomicExch(&partial[g], tot);
        __threadfence();
        unsigned int o2 = atomicAdd(gcount, 1u);   // init 0xFFFFFFFF
        if (o2 == 62u) sflag2 = 1u;                // 64th finisher
    }
    __syncthreads();
    if (sflag2 && tid < 64) {
        // Last finisher: sum the 64 group partials, store the scalar.
        float v = atomicAdd(&partial[tid], 0.0f);
#pragma unroll
        for (int off = 32; off > 0; off >>= 1)
            v += __shfl_down(v, off, 64);
        if (tid == 0) out[0] = v * (1.0f / 131072.0f);
    }
}

extern "C" void kernel_launch(void* const* d_in, const int* in_sizes, int n_in,
                              void* d_out, int out_size, void* d_ws, size_t ws_size,
                              hipStream_t stream)
{
    const float* pred = (const float*)d_in[0];
    const float* gt   = (const float*)d_in[1];
    float* out        = (float*)d_out;
    unsigned int* ws  = (unsigned int*)d_ws;

    // One init: mins + counters to 0xFF (uint-max; counter wrap handled).
    hipMemsetAsync(d_ws, 0xFF, WS_INIT, stream);
    chamfer_fused<<<dim3(1024), dim3(TPB), 0, stream>>>(pred, gt, ws, out);
}

// Round 8
// 144.824 us; speedup vs baseline: 3.6944x; 1.0259x over previous
//
#include <hip/hip_runtime.h>
#include <hip/hip_bf16.h>
#include <math.h>

// ChamferLoss: pred [32,4096,3] f32, gt [32,4096,3] f32 -> scalar f32.
//
// d2(q,t) = p2 + (t2 - 2 q.t); min over t folds only (t2 - 2 q.t); p2 and
// sqrt once per query (sqrt monotone). Inner: 3 v_fma + 1/2 v_min3 per pair
// = 3.5 insts x 2 cyc -> issue floor 47.8 us on 1024 SIMDs.
//
// Model validated: R5 (pk_fma @8cyc) predicted 88.7 vs measured 88.5 us.
// R7 post-mortem: waves_per_eu(4,4) -> unified reg budget 128 -> allocator
// parked query arrays in AGPRs (v_accvgpr_* ~2x inst bloat) -> 92 us.
// R8 = R5 launch config (waves_per_eu(2,2): budget 256, measured VGPR=88,
// no shuffle; grid 512 = 2 blocks/CU, TCH=512) + R7 scalar fma/min3 inner
// (the 157TF path; pk_fma is 8cyc = half rate) + R7 single-dispatch fused
// finish (atomicMin merge + completion counters). ~50us fixed harness
// overhead is outside our control.

#define TPB   256
#define QPT   16            // all 4096 queries of (dir,b) per block
#define NPTS  4096
#define TSPL  8
#define TCH   (NPTS / TSPL) // 512 targets per block (8 KB LDS)
#define NGRP  64            // (dir,b) groups
#define NQTOT (2 * 32 * NPTS)

// ws layout (uints):
//   [0, NQTOT)       : mins[262144]   (init 0xFF; uint order == float order)
//   [NQTOT, +64)     : cnt[64]        (init 0xFF; wrap math handles it)
//   [NQTOT+64, +64)  : float partial[64] (overwritten by finishers)
//   [NQTOT+128]      : gcount         (init 0xFF)
#define WS_INIT ((NQTOT + 129) * 4)

__global__ __attribute__((amdgpu_flat_work_group_size(TPB, TPB)))
__attribute__((amdgpu_waves_per_eu(2, 2)))
void chamfer_fused(const float* __restrict__ pred,
                   const float* __restrict__ gt,
                   unsigned int* __restrict__ ws,
                   float* __restrict__ out)
{
    // grid.x = 512: dir (2) x batch (32) x tsplit (8)
    const int bx  = blockIdx.x;
    const int dir = bx >> 8;
    const int rem = bx & 255;
    const int b   = rem >> 3;
    const int kt  = rem & 7;
    const int g   = dir * 32 + b;

    unsigned int* mins    = ws;
    unsigned int* cnt     = ws + NQTOT;
    float*        partial = (float*)(ws + NQTOT + 64);
    unsigned int* gcount  = ws + NQTOT + 128;

    const float* __restrict__ qbase = (dir ? gt : pred) + (size_t)b * NPTS * 3;
    const float* __restrict__ tbase = (dir ? pred : gt) + (size_t)b * NPTS * 3;

    __shared__ float4 sT[TCH];          // (-2x,-2y,-2z, t2)  8 KB
    __shared__ float swave[TPB / 64];
    __shared__ unsigned int sflag1, sflag2;

    const int tid = threadIdx.x;
    if (tid == 0) { sflag1 = 0u; sflag2 = 0u; }

    // Stage this block's 512-target slice: 2 points per thread
    for (int j = tid; j < TCH; j += TPB) {
        const float* tp = tbase + (size_t)(kt * TCH + j) * 3;
        float x = tp[0], y = tp[1], z = tp[2];
        sT[j] = make_float4(-2.0f * x, -2.0f * y, -2.0f * z,
                            fmaf(x, x, fmaf(y, y, z * z)));
    }

    // 16 queries per thread
    float qx[QPT], qy[QPT], qz[QPT], mn[QPT];
#pragma unroll
    for (int i = 0; i < QPT; ++i) {
        const float* q = qbase + (size_t)(i * TPB + tid) * 3;
        qx[i] = q[0]; qy[i] = q[1]; qz[i] = q[2];
        mn[i] = 1e30f;
    }

    __syncthreads();

    // 2 targets/iter: per query 6 v_fma + 1 v_min3 -> 112 VALU insts per
    // 2 ds_read_b128 (LDS pipe at 43% of VALU issue). 16 independent
    // chains -> issue-saturated at 2 waves/SIMD (R5-verified).
#pragma unroll 2
    for (int j = 0; j < TCH; j += 2) {
        const float4 g0 = sT[j];
        const float4 g1 = sT[j + 1];
#pragma unroll
        for (int i = 0; i < QPT; ++i) {
            float d0 = fmaf(qx[i], g0.x, fmaf(qy[i], g0.y,
                       fmaf(qz[i], g0.z, g0.w)));
            float d1 = fmaf(qx[i], g1.x, fmaf(qy[i], g1.y,
                       fmaf(qz[i], g1.z, g1.w)));
            mn[i] = fminf(fminf(d0, d1), mn[i]);   // v_min3_f32
        }
    }

    // Merge partial mins across the 8 tsplit siblings (d2 > 0 -> uint
    // bit-pattern order == float order; slots init 0xFFFFFFFF = uint max).
    unsigned int* wq = mins + (size_t)g * NPTS;
#pragma unroll
    for (int i = 0; i < QPT; ++i) {
        float p2 = fmaf(qx[i], qx[i], fmaf(qy[i], qy[i], qz[i] * qz[i]));
        float d2 = fmaxf(mn[i] + p2, 1e-12f);
        atomicMin(&wq[i * TPB + tid], __float_as_uint(d2));
    }

    // Group completion: 8th arriver (old == 0xFFFFFFFF + 7 = 6) finishes.
    __syncthreads();
    if (tid == 0) {
        __threadfence();
        unsigned int old = atomicAdd(&cnt[g], 1u);
        if (old == 6u) sflag1 = 1u;
    }
    __syncthreads();

    float s = 0.0f;
    if (sflag1) {
        // Finisher block: sqrt + sum its group's 4096 merged mins.
        // Atomic RMW reads resolve at the device coherence point.
#pragma unroll
        for (int r = 0; r < QPT; ++r) {
            unsigned int u = atomicAdd(&wq[r * TPB + tid], 0u);
            s += sqrtf(__uint_as_float(u));
        }
    }
#pragma unroll
    for (int off = 32; off > 0; off >>= 1)
        s += __shfl_down(s, off, 64);
    const int wid = tid >> 6, lane = tid & 63;
    if (lane == 0) swave[wid] = s;
    __syncthreads();
    if (tid == 0 && sflag1) {
        float tot = swave[0] + swave[1] + swave[2] + swave[3];
        atomicExch(&partial[g], tot);
        __threadfence();
        unsigned int o2 = atomicAdd(gcount, 1u);   // init 0xFFFFFFFF
        if (o2 == 62u) sflag2 = 1u;                // 64th (last) finisher
    }
    __syncthreads();
    if (sflag2 && tid < 64) {
        float v = atomicAdd(&partial[tid], 0.0f);
#pragma unroll
        for (int off = 32; off > 0; off >>= 1)
            v += __shfl_down(v, off, 64);
        if (tid == 0) out[0] = v * (1.0f / 131072.0f);
    }
}

extern "C" void kernel_launch(void* const* d_in, const int* in_sizes, int n_in,
                              void* d_out, int out_size, void* d_ws, size_t ws_size,
                              hipStream_t stream)
{
    const float* pred = (const float*)d_in[0];
    const float* gt   = (const float*)d_in[1];
    float* out        = (float*)d_out;
    unsigned int* ws  = (unsigned int*)d_ws;

    // One init: mins + counters to 0xFF (uint-max; counter wrap handled).
    hipMemsetAsync(d_ws, 0xFF, WS_INIT, stream);
    chamfer_fused<<<dim3(512), dim3(TPB), 0, stream>>>(pred, gt, ws, out);
}